// Round 1
// baseline (114.912 us; speedup 1.0000x reference)
//
#include <hip/hip_runtime.h>
#include <hip/hip_bf16.h>
#include <math.h>

// Problem constants
#define BS_    512
#define NA_    10
#define NE_    11
#define NAL_   9
#define H_     64
#define HEADS_ 4
#define EDIM_  8
#define ADIM_  8
#define OWN_   14
#define HYP_   64
#define NTOT_  (BS_*NA_)   // 5120

// ws float offsets (folded weights)
#define WBIG_OFF 0         // [1040][64]: rows 0..511 W2e'', 512..1023 W2a'', 1024..1031 b2e', 1032..1039 b2a'
#define WCT_OFF  66560     // [64][64]  WcT[h'][k] = sum_j wo[j]*he_w2[2048+j*64+h'][k]
#define WB_OFF   70656     // [64]      wb[k] = sum_j wo[j]*he_w2[2304+j][k]
#define BB_OFF   70720     // [64]      bb[h'] = sum_j wo[j]*he_b2[2048+j*64+h']
#define CC_OFF   70784     // [1]       cconst = sum_j wo[j]*he_b2[2304+j]
#define FC1T_OFF 70848     // [14][64]  fc1_own_w transposed
#define IHT_OFF  71744     // [64][192] gru_w_ih transposed
#define HHT_OFF  84032     // [64][192] gru_w_hh transposed
#define WS_FLOATS 96320

__global__ __launch_bounds__(256) void prep_kernel(
    const float* __restrict__ fc1_own_w,
    const float* __restrict__ he_w2, const float* __restrict__ he_b2,
    const float* __restrict__ ha_w2, const float* __restrict__ ha_b2,
    const float* __restrict__ merge_in_w,
    const float* __restrict__ gru_w_ih, const float* __restrict__ gru_w_hh,
    const float* __restrict__ merge_out_w,
    float* __restrict__ ws)
{
    const int tid = blockIdx.x * blockDim.x + threadIdx.x;

    // w_out = softmax(merge_out_w) over 4 heads
    float wo0, wo1, wo2, wo3;
    {
        float e0 = expf(merge_out_w[0]), e1 = expf(merge_out_w[1]);
        float e2 = expf(merge_out_w[2]), e3 = expf(merge_out_w[3]);
        float inv = 1.0f / (e0 + e1 + e2 + e3);
        wo0 = e0*inv; wo1 = e1*inv; wo2 = e2*inv; wo3 = e3*inv;
    }

    if (tid < 66560) {
        const int idx = tid >> 6;   // 0..1039
        const int hp  = tid & 63;
        // w_in[head][hp] = softmax over heads
        float e0 = expf(merge_in_w[0*64 + hp]), e1 = expf(merge_in_w[1*64 + hp]);
        float e2 = expf(merge_in_w[2*64 + hp]), e3 = expf(merge_in_w[3*64 + hp]);
        float inv = 1.0f / (e0 + e1 + e2 + e3);
        const float wi[4] = { e0*inv, e1*inv, e2*inv, e3*inv };
        float v = 0.f;
        if (idx < 512) {
            const int e = idx >> 6, k = idx & 63;
#pragma unroll
            for (int hd = 0; hd < 4; hd++)
                v += wi[hd] * he_w2[(e*256 + hd*64 + hp)*64 + k];
        } else if (idx < 1024) {
            const int e = (idx - 512) >> 6, k = idx & 63;
#pragma unroll
            for (int hd = 0; hd < 4; hd++)
                v += wi[hd] * ha_w2[(e*256 + hd*64 + hp)*64 + k];
        } else if (idx < 1032) {
            const int e = idx - 1024;
#pragma unroll
            for (int hd = 0; hd < 4; hd++)
                v += wi[hd] * he_b2[e*256 + hd*64 + hp];
        } else {
            const int e = idx - 1032;
#pragma unroll
            for (int hd = 0; hd < 4; hd++)
                v += wi[hd] * ha_b2[e*256 + hd*64 + hp];
        }
        ws[WBIG_OFF + tid] = v;
    } else if (tid < 70656) {
        const int t = tid - 66560;
        const int hp = t >> 6, k = t & 63;
        float v = wo0 * he_w2[(2048 + 0*64 + hp)*64 + k]
                + wo1 * he_w2[(2048 + 1*64 + hp)*64 + k]
                + wo2 * he_w2[(2048 + 2*64 + hp)*64 + k]
                + wo3 * he_w2[(2048 + 3*64 + hp)*64 + k];
        ws[WCT_OFF + t] = v;
    } else if (tid < 70720) {
        const int k = tid - 70656;
        float v = wo0*he_w2[(2304+0)*64 + k] + wo1*he_w2[(2304+1)*64 + k]
                + wo2*he_w2[(2304+2)*64 + k] + wo3*he_w2[(2304+3)*64 + k];
        ws[WB_OFF + k] = v;
    } else if (tid < 70784) {
        const int hp = tid - 70720;
        float v = wo0*he_b2[2048 + 0*64 + hp] + wo1*he_b2[2048 + 1*64 + hp]
                + wo2*he_b2[2048 + 2*64 + hp] + wo3*he_b2[2048 + 3*64 + hp];
        ws[BB_OFF + hp] = v;
    } else if (tid == 70784) {
        ws[CC_OFF] = wo0*he_b2[2304] + wo1*he_b2[2305] + wo2*he_b2[2306] + wo3*he_b2[2307];
    } else if (tid < 70848) {
        // pad, nothing
    } else if (tid < 71744) {
        const int t = tid - 70848; const int j = t >> 6, hp = t & 63;
        ws[FC1T_OFF + t] = fc1_own_w[hp*OWN_ + j];
    } else if (tid < 84032) {
        const int t = tid - 71744; const int j = t / 192, g = t % 192;
        ws[IHT_OFF + t] = gru_w_ih[g*64 + j];
    } else if (tid < 96320) {
        const int t = tid - 84032; const int j = t / 192, g = t % 192;
        ws[HHT_OFF + t] = gru_w_hh[g*64 + j];
    }
}

__global__ __launch_bounds__(64) void main_kernel(
    const float* __restrict__ own_feats,
    const float* __restrict__ enemy_feats,
    const float* __restrict__ ally_feats,
    const float* __restrict__ hidden_state,
    const int*   __restrict__ agent_idx,
    const int*   __restrict__ last_act,
    const float* __restrict__ fc1_own_b,
    const float* __restrict__ agent_emb,
    const float* __restrict__ action_emb,
    const float* __restrict__ he_w1,
    const float* __restrict__ he_b1,
    const float* __restrict__ ha_w1,
    const float* __restrict__ ha_b1,
    const float* __restrict__ fc2_w,
    const float* __restrict__ fc2_b,
    const float* __restrict__ gru_b_ih,
    const float* __restrict__ gru_b_hh,
    const float* __restrict__ ws,
    float* __restrict__ out)
{
    const int lane = threadIdx.x;   // 0..63, one wave per block
    const int n0 = blockIdx.x * 4;  // 4 agents per wave

    __shared__ float a_lds[4][1040];
    __shared__ float x_lds[4][64];
    __shared__ float hin_lds[4][64];
    __shared__ float hh_lds[4][64];

    // hypernet fc1 weight rows for this lane (lane = hidden unit k)
    const float4 w1a  = *(const float4*)(he_w1 + lane*8);
    const float4 w1b  = *(const float4*)(he_w1 + lane*8 + 4);
    const float  hb1  = he_b1[lane];
    const float4 wa1a = *(const float4*)(ha_w1 + lane*8);
    const float4 wa1b = *(const float4*)(ha_w1 + lane*8 + 4);
    const float  hba1 = ha_b1[lane];

    float emb_acc[4];

#pragma unroll
    for (int nn = 0; nn < 4; nn++) {
        const int n = n0 + nn;

        // ---- enemies: hid + rank-1 Psum accumulation ----
        float ps[8] = {0,0,0,0,0,0,0,0};
        for (int ei = 0; ei < NE_; ei++) {
            const float* ef = enemy_feats + (size_t)(n*NE_ + ei)*EDIM_;
            const float4 e0 = *(const float4*)ef;
            const float4 e1 = *(const float4*)(ef + 4);
            float h = hb1;
            h = fmaf(e0.x, w1a.x, h); h = fmaf(e0.y, w1a.y, h);
            h = fmaf(e0.z, w1a.z, h); h = fmaf(e0.w, w1a.w, h);
            h = fmaf(e1.x, w1b.x, h); h = fmaf(e1.y, w1b.y, h);
            h = fmaf(e1.z, w1b.z, h); h = fmaf(e1.w, w1b.w, h);
            h = fmaxf(h, 0.f);
            ps[0] = fmaf(e0.x, h, ps[0]); ps[1] = fmaf(e0.y, h, ps[1]);
            ps[2] = fmaf(e0.z, h, ps[2]); ps[3] = fmaf(e0.w, h, ps[3]);
            ps[4] = fmaf(e1.x, h, ps[4]); ps[5] = fmaf(e1.y, h, ps[5]);
            ps[6] = fmaf(e1.z, h, ps[6]); ps[7] = fmaf(e1.w, h, ps[7]);
        }
#pragma unroll
        for (int e = 0; e < 8; e++) a_lds[nn][e*64 + lane] = ps[e];

        // ---- allies ----
        float pa[8] = {0,0,0,0,0,0,0,0};
        for (int ai = 0; ai < NAL_; ai++) {
            const float* af = ally_feats + (size_t)(n*NAL_ + ai)*ADIM_;
            const float4 a0 = *(const float4*)af;
            const float4 a1 = *(const float4*)(af + 4);
            float h = hba1;
            h = fmaf(a0.x, wa1a.x, h); h = fmaf(a0.y, wa1a.y, h);
            h = fmaf(a0.z, wa1a.z, h); h = fmaf(a0.w, wa1a.w, h);
            h = fmaf(a1.x, wa1b.x, h); h = fmaf(a1.y, wa1b.y, h);
            h = fmaf(a1.z, wa1b.z, h); h = fmaf(a1.w, wa1b.w, h);
            h = fmaxf(h, 0.f);
            pa[0] = fmaf(a0.x, h, pa[0]); pa[1] = fmaf(a0.y, h, pa[1]);
            pa[2] = fmaf(a0.z, h, pa[2]); pa[3] = fmaf(a0.w, h, pa[3]);
            pa[4] = fmaf(a1.x, h, pa[4]); pa[5] = fmaf(a1.y, h, pa[5]);
            pa[6] = fmaf(a1.z, h, pa[6]); pa[7] = fmaf(a1.w, h, pa[7]);
        }
#pragma unroll
        for (int e = 0; e < 8; e++) a_lds[nn][512 + e*64 + lane] = pa[e];

        // feature sums (pair with folded bias rows)
        if (lane < 8) {
            float s = 0.f;
            for (int ei = 0; ei < NE_; ei++) s += enemy_feats[(size_t)(n*NE_ + ei)*EDIM_ + lane];
            a_lds[nn][1024 + lane] = s;
            float s2 = 0.f;
            for (int ai = 0; ai < NAL_; ai++) s2 += ally_feats[(size_t)(n*NAL_ + ai)*ADIM_ + lane];
            a_lds[nn][1032 + lane] = s2;
        }

        // emb_own
        float e = fc1_own_b[lane];
        const float* ow = own_feats + (size_t)n*OWN_;
        for (int j = 0; j < OWN_; j++) e = fmaf(ow[j], ws[FC1T_OFF + j*64 + lane], e);
        e += agent_emb[agent_idx[n]*64 + lane];
        e += action_emb[last_act[n]*64 + lane];
        emb_acc[nn] = e;
        hin_lds[nn][lane] = hidden_state[(size_t)n*64 + lane];
    }
    __syncthreads();

    // ---- big folded dot: emb[h'] += sum_idx a[idx] * Wbig[idx][h'] ----
    const float* WBp = ws + WBIG_OFF;
    for (int idx = 0; idx < 1040; idx += 4) {
        const float w0 = WBp[(idx+0)*64 + lane];
        const float w1 = WBp[(idx+1)*64 + lane];
        const float w2 = WBp[(idx+2)*64 + lane];
        const float w3 = WBp[(idx+3)*64 + lane];
#pragma unroll
        for (int nn = 0; nn < 4; nn++) {
            const float4 aa = *(const float4*)&a_lds[nn][idx];
            float acc = emb_acc[nn];
            acc = fmaf(aa.x, w0, acc);
            acc = fmaf(aa.y, w1, acc);
            acc = fmaf(aa.z, w2, acc);
            acc = fmaf(aa.w, w3, acc);
            emb_acc[nn] = acc;
        }
    }
#pragma unroll
    for (int nn = 0; nn < 4; nn++) x_lds[nn][lane] = fmaxf(emb_acc[nn], 0.f);
    __syncthreads();

    // ---- GRU ----
    float gr[4], gz[4], gn[4], hr[4], hz[4], hn[4];
    {
        const float bir = gru_b_ih[lane], biz = gru_b_ih[64 + lane], bin_ = gru_b_ih[128 + lane];
        const float bhr = gru_b_hh[lane], bhz = gru_b_hh[64 + lane], bhn = gru_b_hh[128 + lane];
#pragma unroll
        for (int nn = 0; nn < 4; nn++) {
            gr[nn] = bir; gz[nn] = biz; gn[nn] = bin_;
            hr[nn] = bhr; hz[nn] = bhz; hn[nn] = bhn;
        }
    }
    const float* IHT = ws + IHT_OFF;
    const float* HHT = ws + HHT_OFF;
    for (int j = 0; j < 64; j++) {
        const float wr = IHT[j*192 + lane];
        const float wz = IHT[j*192 + 64 + lane];
        const float wn = IHT[j*192 + 128 + lane];
        const float vr = HHT[j*192 + lane];
        const float vz = HHT[j*192 + 64 + lane];
        const float vn = HHT[j*192 + 128 + lane];
#pragma unroll
        for (int nn = 0; nn < 4; nn++) {
            const float xj = x_lds[nn][j];
            const float hj = hin_lds[nn][j];
            gr[nn] = fmaf(xj, wr, gr[nn]);
            gz[nn] = fmaf(xj, wz, gz[nn]);
            gn[nn] = fmaf(xj, wn, gn[nn]);
            hr[nn] = fmaf(hj, vr, hr[nn]);
            hz[nn] = fmaf(hj, vz, hz[nn]);
            hn[nn] = fmaf(hj, vn, hn[nn]);
        }
    }
    float hh[4];
#pragma unroll
    for (int nn = 0; nn < 4; nn++) {
        const float r = 1.f / (1.f + expf(-(gr[nn] + hr[nn])));
        const float z = 1.f / (1.f + expf(-(gz[nn] + hz[nn])));
        const float t = tanhf(gn[nn] + r*hn[nn]);
        const float hp = hin_lds[nn][lane];
        hh[nn] = (1.f - z)*t + z*hp;
        hh_lds[nn][lane] = hh[nn];
    }
    __syncthreads();

    // ---- q_normal (6 outputs per agent) ----
#pragma unroll
    for (int nn = 0; nn < 4; nn++) {
        if (lane < 6) {
            float s = fc2_b[lane];
            for (int j = 0; j < 64; j++) s = fmaf(hh_lds[nn][j], fc2_w[lane*64 + j], s);
            out[(size_t)(n0 + nn)*17 + lane] = s;
        }
    }

    // ---- v' = Wc.hh + wb ; s_n = hh.bb + cconst ----
    float vv[4], sn[4];
#pragma unroll
    for (int nn = 0; nn < 4; nn++) {
        float v = ws[WB_OFF + lane];
        for (int j = 0; j < 64; j++) v = fmaf(hh_lds[nn][j], ws[WCT_OFF + j*64 + lane], v);
        vv[nn] = v;
        float p = hh[nn] * ws[BB_OFF + lane];
#pragma unroll
        for (int off = 32; off; off >>= 1) p += __shfl_xor(p, off);
        sn[nn] = p + ws[CC_OFF];
    }

    // ---- q_attack: recompute enemy hid, dot with v' ----
#pragma unroll
    for (int nn = 0; nn < 4; nn++) {
        const int n = n0 + nn;
        for (int ei = 0; ei < NE_; ei++) {
            const float* ef = enemy_feats + (size_t)(n*NE_ + ei)*EDIM_;
            const float4 e0 = *(const float4*)ef;
            const float4 e1 = *(const float4*)(ef + 4);
            float h = hb1;
            h = fmaf(e0.x, w1a.x, h); h = fmaf(e0.y, w1a.y, h);
            h = fmaf(e0.z, w1a.z, h); h = fmaf(e0.w, w1a.w, h);
            h = fmaf(e1.x, w1b.x, h); h = fmaf(e1.y, w1b.y, h);
            h = fmaf(e1.z, w1b.z, h); h = fmaf(e1.w, w1b.w, h);
            h = fmaxf(h, 0.f);
            float p = vv[nn] * h;
#pragma unroll
            for (int off = 32; off; off >>= 1) p += __shfl_xor(p, off);
            if (lane == 0) out[(size_t)n*17 + 6 + ei] = p + sn[nn];
        }
    }
}

extern "C" void kernel_launch(void* const* d_in, const int* in_sizes, int n_in,
                              void* d_out, int out_size, void* d_ws, size_t ws_size,
                              hipStream_t stream)
{
    const float* own_feats   = (const float*)d_in[0];
    const float* enemy_feats = (const float*)d_in[1];
    const float* ally_feats  = (const float*)d_in[2];
    const float* hidden      = (const float*)d_in[3];
    const int*   agent_idx   = (const int*)d_in[4];
    const int*   last_act    = (const int*)d_in[5];
    const float* fc1_own_w   = (const float*)d_in[6];
    const float* fc1_own_b   = (const float*)d_in[7];
    const float* agent_emb   = (const float*)d_in[8];
    const float* action_emb  = (const float*)d_in[9];
    const float* he_w1       = (const float*)d_in[10];
    const float* he_b1       = (const float*)d_in[11];
    const float* he_w2       = (const float*)d_in[12];
    const float* he_b2       = (const float*)d_in[13];
    const float* ha_w1       = (const float*)d_in[14];
    const float* ha_b1       = (const float*)d_in[15];
    const float* ha_w2       = (const float*)d_in[16];
    const float* ha_b2       = (const float*)d_in[17];
    const float* merge_in_w  = (const float*)d_in[18];
    const float* gru_w_ih    = (const float*)d_in[19];
    const float* gru_w_hh    = (const float*)d_in[20];
    const float* gru_b_ih    = (const float*)d_in[21];
    const float* gru_b_hh    = (const float*)d_in[22];
    const float* fc2_w       = (const float*)d_in[23];
    const float* fc2_b       = (const float*)d_in[24];
    const float* merge_out_w = (const float*)d_in[25];
    float* out = (float*)d_out;
    float* ws  = (float*)d_ws;

    hipLaunchKernelGGL(prep_kernel, dim3(377), dim3(256), 0, stream,
                       fc1_own_w, he_w2, he_b2, ha_w2, ha_b2, merge_in_w,
                       gru_w_ih, gru_w_hh, merge_out_w, ws);
    hipLaunchKernelGGL(main_kernel, dim3(NTOT_/4), dim3(64), 0, stream,
                       own_feats, enemy_feats, ally_feats, hidden, agent_idx, last_act,
                       fc1_own_b, agent_emb, action_emb, he_w1, he_b1, ha_w1, ha_b1,
                       fc2_w, fc2_b, gru_b_ih, gru_b_hh, ws, out);
}

// Round 2
// 72.710 us; speedup vs baseline: 1.5804x; 1.5804x over previous
//
#include <hip/hip_runtime.h>
#include <hip/hip_bf16.h>
#include <math.h>

// Problem constants
#define BS_    512
#define NA_    10
#define NE_    11
#define NAL_   9
#define H_     64
#define HEADS_ 4
#define EDIM_  8
#define ADIM_  8
#define OWN_   14
#define HYP_   64
#define NTOT_  (BS_*NA_)   // 5120

// ws float offsets (folded weights)
#define WBIG_OFF 0         // [1040][64]: rows 0..511 W2e'', 512..1023 W2a'', 1024..1031 b2e', 1032..1039 b2a'
#define WCT_OFF  66560     // [64][64]  WcT[h'][k]
#define WB_OFF   70656     // [64]
#define BB_OFF   70720     // [64]
#define CC_OFF   70784     // [1]
#define FC1T_OFF 70848     // [14][64]  fc1_own_w transposed
#define IHT_OFF  71744     // [64][192] gru_w_ih transposed
#define HHT_OFF  84032     // [64][192] gru_w_hh transposed
#define WS_FLOATS 96320

__global__ __launch_bounds__(256) void prep_kernel(
    const float* __restrict__ fc1_own_w,
    const float* __restrict__ he_w2, const float* __restrict__ he_b2,
    const float* __restrict__ ha_w2, const float* __restrict__ ha_b2,
    const float* __restrict__ merge_in_w,
    const float* __restrict__ gru_w_ih, const float* __restrict__ gru_w_hh,
    const float* __restrict__ merge_out_w,
    float* __restrict__ ws)
{
    const int tid = blockIdx.x * blockDim.x + threadIdx.x;

    float wo0, wo1, wo2, wo3;
    {
        float e0 = expf(merge_out_w[0]), e1 = expf(merge_out_w[1]);
        float e2 = expf(merge_out_w[2]), e3 = expf(merge_out_w[3]);
        float inv = 1.0f / (e0 + e1 + e2 + e3);
        wo0 = e0*inv; wo1 = e1*inv; wo2 = e2*inv; wo3 = e3*inv;
    }

    if (tid < 66560) {
        const int idx = tid >> 6;   // 0..1039
        const int hp  = tid & 63;
        float e0 = expf(merge_in_w[0*64 + hp]), e1 = expf(merge_in_w[1*64 + hp]);
        float e2 = expf(merge_in_w[2*64 + hp]), e3 = expf(merge_in_w[3*64 + hp]);
        float inv = 1.0f / (e0 + e1 + e2 + e3);
        const float wi[4] = { e0*inv, e1*inv, e2*inv, e3*inv };
        float v = 0.f;
        if (idx < 512) {
            const int e = idx >> 6, k = idx & 63;
#pragma unroll
            for (int hd = 0; hd < 4; hd++)
                v += wi[hd] * he_w2[(e*256 + hd*64 + hp)*64 + k];
        } else if (idx < 1024) {
            const int e = (idx - 512) >> 6, k = idx & 63;
#pragma unroll
            for (int hd = 0; hd < 4; hd++)
                v += wi[hd] * ha_w2[(e*256 + hd*64 + hp)*64 + k];
        } else if (idx < 1032) {
            const int e = idx - 1024;
#pragma unroll
            for (int hd = 0; hd < 4; hd++)
                v += wi[hd] * he_b2[e*256 + hd*64 + hp];
        } else {
            const int e = idx - 1032;
#pragma unroll
            for (int hd = 0; hd < 4; hd++)
                v += wi[hd] * ha_b2[e*256 + hd*64 + hp];
        }
        ws[WBIG_OFF + tid] = v;
    } else if (tid < 70656) {
        const int t = tid - 66560;
        const int hp = t >> 6, k = t & 63;
        float v = wo0 * he_w2[(2048 + 0*64 + hp)*64 + k]
                + wo1 * he_w2[(2048 + 1*64 + hp)*64 + k]
                + wo2 * he_w2[(2048 + 2*64 + hp)*64 + k]
                + wo3 * he_w2[(2048 + 3*64 + hp)*64 + k];
        ws[WCT_OFF + t] = v;
    } else if (tid < 70720) {
        const int k = tid - 70656;
        float v = wo0*he_w2[(2304+0)*64 + k] + wo1*he_w2[(2304+1)*64 + k]
                + wo2*he_w2[(2304+2)*64 + k] + wo3*he_w2[(2304+3)*64 + k];
        ws[WB_OFF + k] = v;
    } else if (tid < 70784) {
        const int hp = tid - 70720;
        float v = wo0*he_b2[2048 + 0*64 + hp] + wo1*he_b2[2048 + 1*64 + hp]
                + wo2*he_b2[2048 + 2*64 + hp] + wo3*he_b2[2048 + 3*64 + hp];
        ws[BB_OFF + hp] = v;
    } else if (tid == 70784) {
        ws[CC_OFF] = wo0*he_b2[2304] + wo1*he_b2[2305] + wo2*he_b2[2306] + wo3*he_b2[2307];
    } else if (tid < 70848) {
        // pad
    } else if (tid < 71744) {
        const int t = tid - 70848; const int j = t >> 6, hp = t & 63;
        ws[FC1T_OFF + t] = fc1_own_w[hp*OWN_ + j];
    } else if (tid < 84032) {
        const int t = tid - 71744; const int j = t / 192, g = t % 192;
        ws[IHT_OFF + t] = gru_w_ih[g*64 + j];
    } else if (tid < 96320) {
        const int t = tid - 84032; const int j = t / 192, g = t % 192;
        ws[HHT_OFF + t] = gru_w_hh[g*64 + j];
    }
}

__device__ __forceinline__ float wave_red(float v) {
#pragma unroll
    for (int off = 32; off; off >>= 1) v += __shfl_xor(v, off);
    return v;
}

__global__ __launch_bounds__(256) void main_kernel(
    const float* __restrict__ own_feats,
    const float* __restrict__ enemy_feats,
    const float* __restrict__ ally_feats,
    const float* __restrict__ hidden_state,
    const int*   __restrict__ agent_idx,
    const int*   __restrict__ last_act,
    const float* __restrict__ fc1_own_b,
    const float* __restrict__ agent_emb,
    const float* __restrict__ action_emb,
    const float* __restrict__ he_w1,
    const float* __restrict__ he_b1,
    const float* __restrict__ ha_w1,
    const float* __restrict__ ha_b1,
    const float* __restrict__ fc2_w,
    const float* __restrict__ fc2_b,
    const float* __restrict__ gru_b_ih,
    const float* __restrict__ gru_b_hh,
    const float* __restrict__ ws,
    float* __restrict__ out)
{
    const int tid  = threadIdx.x;
    const int w    = tid >> 6;        // wave id 0..3
    const int lane = tid & 63;
    const int n0   = blockIdx.x * 4;
    const int n    = n0 + w;          // this wave's agent

    __shared__ float a_lds[4][1040];
    __shared__ float pemb[4][4][64];
    __shared__ float x_lds[4][68];
    __shared__ float hin_lds[4][68];
    __shared__ float hh_lds[4][68];

    // ================= Phase 1: per-agent activations (1 agent per wave) ====
    float h_e[NE_];
    float embo;
    {
        const float4 w1a  = *(const float4*)(he_w1 + lane*8);
        const float4 w1b  = *(const float4*)(he_w1 + lane*8 + 4);
        const float  hb1  = he_b1[lane];

        float ps[8] = {0,0,0,0,0,0,0,0};
#pragma unroll
        for (int ei = 0; ei < NE_; ei++) {
            const float* ef = enemy_feats + (size_t)(n*NE_ + ei)*EDIM_;
            const float4 e0 = *(const float4*)ef;
            const float4 e1 = *(const float4*)(ef + 4);
            float h = hb1;
            h = fmaf(e0.x, w1a.x, h); h = fmaf(e0.y, w1a.y, h);
            h = fmaf(e0.z, w1a.z, h); h = fmaf(e0.w, w1a.w, h);
            h = fmaf(e1.x, w1b.x, h); h = fmaf(e1.y, w1b.y, h);
            h = fmaf(e1.z, w1b.z, h); h = fmaf(e1.w, w1b.w, h);
            h = fmaxf(h, 0.f);
            h_e[ei] = h;
            ps[0] = fmaf(e0.x, h, ps[0]); ps[1] = fmaf(e0.y, h, ps[1]);
            ps[2] = fmaf(e0.z, h, ps[2]); ps[3] = fmaf(e0.w, h, ps[3]);
            ps[4] = fmaf(e1.x, h, ps[4]); ps[5] = fmaf(e1.y, h, ps[5]);
            ps[6] = fmaf(e1.z, h, ps[6]); ps[7] = fmaf(e1.w, h, ps[7]);
        }
#pragma unroll
        for (int e = 0; e < 8; e++) a_lds[w][e*64 + lane] = ps[e];

        const float4 wa1a = *(const float4*)(ha_w1 + lane*8);
        const float4 wa1b = *(const float4*)(ha_w1 + lane*8 + 4);
        const float  hba1 = ha_b1[lane];
        float pa[8] = {0,0,0,0,0,0,0,0};
#pragma unroll
        for (int ai = 0; ai < NAL_; ai++) {
            const float* af = ally_feats + (size_t)(n*NAL_ + ai)*ADIM_;
            const float4 a0 = *(const float4*)af;
            const float4 a1 = *(const float4*)(af + 4);
            float h = hba1;
            h = fmaf(a0.x, wa1a.x, h); h = fmaf(a0.y, wa1a.y, h);
            h = fmaf(a0.z, wa1a.z, h); h = fmaf(a0.w, wa1a.w, h);
            h = fmaf(a1.x, wa1b.x, h); h = fmaf(a1.y, wa1b.y, h);
            h = fmaf(a1.z, wa1b.z, h); h = fmaf(a1.w, wa1b.w, h);
            h = fmaxf(h, 0.f);
            pa[0] = fmaf(a0.x, h, pa[0]); pa[1] = fmaf(a0.y, h, pa[1]);
            pa[2] = fmaf(a0.z, h, pa[2]); pa[3] = fmaf(a0.w, h, pa[3]);
            pa[4] = fmaf(a1.x, h, pa[4]); pa[5] = fmaf(a1.y, h, pa[5]);
            pa[6] = fmaf(a1.z, h, pa[6]); pa[7] = fmaf(a1.w, h, pa[7]);
        }
#pragma unroll
        for (int e = 0; e < 8; e++) a_lds[w][512 + e*64 + lane] = pa[e];

        // feature sums (pair with folded bias rows); split across lanes 0..15
        if (lane < 8) {
            float s = 0.f;
            for (int ei = 0; ei < NE_; ei++) s += enemy_feats[(size_t)(n*NE_ + ei)*EDIM_ + lane];
            a_lds[w][1024 + lane] = s;
        } else if (lane < 16) {
            const int p = lane - 8;
            float s = 0.f;
            for (int ai = 0; ai < NAL_; ai++) s += ally_feats[(size_t)(n*NAL_ + ai)*ADIM_ + p];
            a_lds[w][1032 + p] = s;
        }

        // emb_own
        float e = fc1_own_b[lane];
        const float* ow = own_feats + (size_t)n*OWN_;
#pragma unroll
        for (int j = 0; j < OWN_; j++) e = fmaf(ow[j], ws[FC1T_OFF + j*64 + lane], e);
        e += agent_emb[agent_idx[n]*64 + lane];
        e += action_emb[last_act[n]*64 + lane];
        embo = e;

        hin_lds[w][lane] = hidden_state[(size_t)n*64 + lane];
    }
    __syncthreads();

    // ================= Phase 2: folded dot, K-split across waves ============
    {
        float acc[4];
#pragma unroll
        for (int nn = 0; nn < 4; nn++) acc[nn] = (nn == w) ? embo : 0.f;

        const float* WBp = ws + WBIG_OFF;
        const int r0 = w * 260;
#pragma unroll 2
        for (int idx = r0; idx < r0 + 260; idx += 4) {
            const float w0 = WBp[(idx+0)*64 + lane];
            const float w1 = WBp[(idx+1)*64 + lane];
            const float w2 = WBp[(idx+2)*64 + lane];
            const float w3 = WBp[(idx+3)*64 + lane];
#pragma unroll
            for (int nn = 0; nn < 4; nn++) {
                const float4 aa = *(const float4*)&a_lds[nn][idx];
                float a = acc[nn];
                a = fmaf(aa.x, w0, a);
                a = fmaf(aa.y, w1, a);
                a = fmaf(aa.z, w2, a);
                a = fmaf(aa.w, w3, a);
                acc[nn] = a;
            }
        }
#pragma unroll
        for (int nn = 0; nn < 4; nn++) pemb[w][nn][lane] = acc[nn];
    }
    __syncthreads();

    // finalize emb for agent w, write x
    {
        const float emb = pemb[0][w][lane] + pemb[1][w][lane]
                        + pemb[2][w][lane] + pemb[3][w][lane];
        x_lds[w][lane] = fmaxf(emb, 0.f);
    }
    __syncthreads();

    // ================= GRU: lane = (agent, unit16), block-shared weights ====
    {
        const int ag = lane >> 4;
        const int k  = (w << 4) + (lane & 15);
        float gr = gru_b_ih[k], gz = gru_b_ih[64 + k], gn = gru_b_ih[128 + k];
        float hr = gru_b_hh[k], hz = gru_b_hh[64 + k], hn = gru_b_hh[128 + k];
        const float* IHT = ws + IHT_OFF;
        const float* HHT = ws + HHT_OFF;
        for (int j = 0; j < 64; j++) {
            const float xj = x_lds[ag][j];
            const float hj = hin_lds[ag][j];
            gr = fmaf(xj, IHT[j*192 + k],       gr);
            gz = fmaf(xj, IHT[j*192 + 64 + k],  gz);
            gn = fmaf(xj, IHT[j*192 + 128 + k], gn);
            hr = fmaf(hj, HHT[j*192 + k],       hr);
            hz = fmaf(hj, HHT[j*192 + 64 + k],  hz);
            hn = fmaf(hj, HHT[j*192 + 128 + k], hn);
        }
        const float r = 1.f / (1.f + expf(-(gr + hr)));
        const float z = 1.f / (1.f + expf(-(gz + hz)));
        const float t = tanhf(gn + r * hn);
        const float hp = hin_lds[ag][k];
        hh_lds[ag][k] = (1.f - z) * t + z * hp;
    }
    __syncthreads();

    // ================= Epilogue for agent w =================================
    {
        const float hh = hh_lds[w][lane];

        // q_normal: 6 outputs
#pragma unroll
        for (int l = 0; l < 6; l++) {
            const float p = wave_red(hh * fc2_w[l*64 + lane]);
            if (lane == 0) out[(size_t)n*17 + l] = p + fc2_b[l];
        }

        // vv = Wc.hh + wb
        float vv = ws[WB_OFF + lane];
        for (int j = 0; j < 64; j++)
            vv = fmaf(hh_lds[w][j], ws[WCT_OFF + j*64 + lane], vv);

        // sn = hh.bb + cc
        const float sn = wave_red(hh * ws[BB_OFF + lane]) + ws[CC_OFF];

        // q_attack
#pragma unroll
        for (int ei = 0; ei < NE_; ei++) {
            const float q = wave_red(vv * h_e[ei]);
            if (lane == 0) out[(size_t)n*17 + 6 + ei] = q + sn;
        }
    }
}

extern "C" void kernel_launch(void* const* d_in, const int* in_sizes, int n_in,
                              void* d_out, int out_size, void* d_ws, size_t ws_size,
                              hipStream_t stream)
{
    const float* own_feats   = (const float*)d_in[0];
    const float* enemy_feats = (const float*)d_in[1];
    const float* ally_feats  = (const float*)d_in[2];
    const float* hidden      = (const float*)d_in[3];
    const int*   agent_idx   = (const int*)d_in[4];
    const int*   last_act    = (const int*)d_in[5];
    const float* fc1_own_w   = (const float*)d_in[6];
    const float* fc1_own_b   = (const float*)d_in[7];
    const float* agent_emb   = (const float*)d_in[8];
    const float* action_emb  = (const float*)d_in[9];
    const float* he_w1       = (const float*)d_in[10];
    const float* he_b1       = (const float*)d_in[11];
    const float* he_w2       = (const float*)d_in[12];
    const float* he_b2       = (const float*)d_in[13];
    const float* ha_w1       = (const float*)d_in[14];
    const float* ha_b1       = (const float*)d_in[15];
    const float* ha_w2       = (const float*)d_in[16];
    const float* ha_b2       = (const float*)d_in[17];
    const float* merge_in_w  = (const float*)d_in[18];
    const float* gru_w_ih    = (const float*)d_in[19];
    const float* gru_w_hh    = (const float*)d_in[20];
    const float* gru_b_ih    = (const float*)d_in[21];
    const float* gru_b_hh    = (const float*)d_in[22];
    const float* fc2_w       = (const float*)d_in[23];
    const float* fc2_b       = (const float*)d_in[24];
    const float* merge_out_w = (const float*)d_in[25];
    float* out = (float*)d_out;
    float* ws  = (float*)d_ws;

    hipLaunchKernelGGL(prep_kernel, dim3(377), dim3(256), 0, stream,
                       fc1_own_w, he_w2, he_b2, ha_w2, ha_b2, merge_in_w,
                       gru_w_ih, gru_w_hh, merge_out_w, ws);
    hipLaunchKernelGGL(main_kernel, dim3(NTOT_/4), dim3(256), 0, stream,
                       own_feats, enemy_feats, ally_feats, hidden, agent_idx, last_act,
                       fc1_own_b, agent_emb, action_emb, he_w1, he_b1, ha_w1, ha_b1,
                       fc2_w, fc2_b, gru_b_ih, gru_b_hh, ws, out);
}